// Round 21
// baseline (569.966 us; speedup 1.0000x reference)
//
#include <hip/hip_runtime.h>
#include <hip/hip_bf16.h>
#include <stdint.h>

typedef __attribute__((ext_vector_type(8))) short bf16x8;
typedef __attribute__((ext_vector_type(4))) float f32x4;

// Contraction-proof single f32 ops (np emulation must stay unfused).
__device__ __forceinline__ float vmulf(float a, float b) {
    float d; asm volatile("v_mul_f32 %0, %1, %2" : "=v"(d) : "v"(a), "v"(b)); return d;
}
__device__ __forceinline__ float vaddf(float a, float b) {
    float d; asm volatile("v_add_f32 %0, %1, %2" : "=v"(d) : "v"(a), "v"(b)); return d;
}
__device__ __forceinline__ float vsubf(float a, float b) {
    float d; asm volatile("v_sub_f32 %0, %1, %2" : "=v"(d) : "v"(a), "v"(b)); return d;
}

__device__ __forceinline__ short bf16h(float v) {
    __hip_bfloat16 h = __float2bfloat16(v);
    return *(short*)&h;
}
__device__ __forceinline__ float bf16f(short s) {
    return __uint_as_float(((unsigned int)(unsigned short)s) << 16);
}
__device__ __forceinline__ void split2(float v, short& h, short& m) {
    h = bf16h(v);
    m = bf16h(__fsub_rn(v, bf16f(h)));
}

__device__ __forceinline__ float decode_scalar(const void* p, float dflt) {
    float f = *(const float*)p;
    if (!(f == f) || fabsf(f) > 1.0e6f) return dflt;
    return f;
}
__device__ __forceinline__ int decode_ts(const void* p) {
    int w = *(const int*)p;
    if (w >= 1 && w <= 100000) return w;
    return 32;
}

#define LDA 36   // LDS row stride for B: 16B-aligned b128, 2-way banks (free)

// -------- k1a: one BLIS KC=512 panel per block (exact ascending-k chain) ----
// Reference (VERIFIED R17-R20) = AOCL-BLIS zen sgemm: exact KC=512 panels,
// sequential ascending-k IEEE-FMA chain per C element, C = P0 + P1 in order.
// R21: A read directly from global (wave-broadcast rows, L1/L2-served, vmem
// pipe) — only B staged in LDS. Cuts LDS-pipe traffic ~2x; FMA-bound floor.
__global__ __launch_bounds__(256) void k1_panel_gemm(
    const float* __restrict__ X,    // [M,K] fp32
    const float* __restrict__ W1,   // [N,K] fp32
    float* __restrict__ P0,         // [M,N] panel-0 out (spikes buffer)
    float* __restrict__ P1,         // [M,N] panel-1 out (workspace)
    int M, int N, int K, int KC)
{
    __shared__ float Bs[128][LDA];

    const int t  = threadIdx.x;
    const int tx = t & 15;
    const int ty = t >> 4;
    const int m0 = blockIdx.x * 128;
    const int n0 = blockIdx.y * 128;
    const int kz = blockIdx.z * KC;
    float* __restrict__ Pout = blockIdx.z ? P1 : P0;

    // Per-lane A row bases (8 rows, broadcast across the 16 tx lanes).
    const float* arow[8];
    #pragma unroll
    for (int i = 0; i < 8; ++i)
        arow[i] = X + (size_t)(m0 + ty + 16 * i) * K + kz;

    float p[8][8] = {};   // this panel's sequential chain

    for (int kt = 0; kt < KC; kt += 32) {
        // Stage B only: 128 rows x 32 k = 1024 float4, 4 per thread.
        #pragma unroll
        for (int cc = 0; cc < 4; ++cc) {
            const int li  = cc * 256 + t;    // 0..1023
            const int row = li >> 3;
            const int q   = li & 7;
            *(float4*)&Bs[row][q * 4] =
                *(const float4*)&W1[(size_t)(n0 + row) * K + kz + kt + q * 4];
        }
        __syncthreads();

        #pragma unroll
        for (int g = 0; g < 8; ++g) {
            float4 af[8], bf[8];
            #pragma unroll
            for (int i = 0; i < 8; ++i)
                af[i] = *(const float4*)&arow[i][kt + g * 4];   // global, bcast
            #pragma unroll
            for (int j = 0; j < 8; ++j)
                bf[j] = *(const float4*)&Bs[tx + 16 * j][g * 4]; // LDS
            #pragma unroll
            for (int kk = 0; kk < 4; ++kk) {
                #pragma unroll
                for (int i = 0; i < 8; ++i) {
                    const float a = ((const float*)&af[i])[kk];
                    #pragma unroll
                    for (int j = 0; j < 8; ++j)
                        p[i][j] = __builtin_fmaf(a, ((const float*)&bf[j])[kk], p[i][j]);
                }
            }
        }
        __syncthreads();
    }

    #pragma unroll
    for (int i = 0; i < 8; ++i) {
        const size_t rowb = (size_t)(m0 + ty + 16 * i) * N;
        #pragma unroll
        for (int j = 0; j < 8; ++j)
            Pout[rowb + n0 + tx + 16 * j] = p[i][j];
    }
}

// -------- k1b: fold c = P0 + P1 (BLIS order) + exact f32 asm-unfused scan ---
__global__ __launch_bounds__(256) void k1_combine_scan(
    const float* __restrict__ P0,
    const float* __restrict__ P1,
    const float* __restrict__ b1,
    const void* tau_mem_p, const void* tau_syn_p,
    const void* v_thresh_p, const void* v_reset_p, const void* ts_p,
    float* __restrict__ spikes, int N, int total4)
{
    const int idx4 = blockIdx.x * 256 + threadIdx.x;
    if (idx4 >= total4) return;

    const float tau_m = decode_scalar(tau_mem_p, 10.0f);
    const float tau_s = decode_scalar(tau_syn_p, 5.0f);
    const float vth   = decode_scalar(v_thresh_p, 1.0f);
    const float vrs   = decode_scalar(v_reset_p, 0.0f);
    const int   ts    = decode_ts(ts_p);
    const float rs    = 1.0f / tau_s;
    const float rm    = 1.0f / tau_m;
    const float ivts  = 1.0f / (float)ts;

    const float4 a = ((const float4*)P0)[idx4];
    const float4 b = ((const float4*)P1)[idx4];
    const int col0 = (idx4 * 4) % N;
    const float4 bb = *(const float4*)&b1[col0];

    float cur[4], iv[4], vv[4], cnt[4];
    const float av[4] = {a.x, a.y, a.z, a.w};
    const float bv[4] = {b.x, b.y, b.z, b.w};
    const float bbv[4] = {bb.x, bb.y, bb.z, bb.w};
    #pragma unroll
    for (int e = 0; e < 4; ++e) {
        const float c = vaddf(av[e], bv[e]);         // BLIS fold: P0 + P1
        cur[e] = vmulf(vaddf(c, bbv[e]), ivts);      // exact /32
        iv[e] = 0.0f; vv[e] = 0.0f; cnt[e] = 0.0f;
    }
    for (int tt = 0; tt < ts; ++tt) {
        #pragma unroll
        for (int e = 0; e < 4; ++e) {
            iv[e] = vaddf(vsubf(iv[e], vmulf(rs, iv[e])), cur[e]);
            vv[e] = vaddf(vsubf(vv[e], vmulf(rm, vv[e])), iv[e]);
            const bool s = (vv[e] >= vth);
            cnt[e] += s ? 1.0f : 0.0f;
            vv[e]   = s ? vrs : vv[e];
        }
    }
    ((float4*)spikes)[idx4] = make_float4(cnt[0], cnt[1], cnt[2], cnt[3]);
}

// -------- fallback k1 (R18, verified): used when ws_size is too small -------
__global__ __launch_bounds__(256) void k1_f32chain_snn(
    const float* __restrict__ X, const float* __restrict__ W1,
    const float* __restrict__ b1,
    const void* tau_mem_p, const void* tau_syn_p,
    const void* v_thresh_p, const void* v_reset_p, const void* ts_p,
    float* __restrict__ spikes, int M, int N, int K, int f0)
{
    __shared__ float As[128][LDA];
    __shared__ float Bs[128][LDA];

    const int t  = threadIdx.x;
    const int tx = t & 15;
    const int ty = t >> 4;
    const int m0 = blockIdx.x * 128;
    const int n0 = blockIdx.y * 128;

    float c[8][8] = {};
    float p[8][8] = {};

    for (int k0 = 0; k0 < K; k0 += 32) {
        #pragma unroll
        for (int cc = 0; cc < 4; ++cc) {
            const int li  = cc * 256 + t;
            const int row = li >> 3;
            const int q   = li & 7;
            *(float4*)&As[row][q * 4] =
                *(const float4*)&X[(size_t)(m0 + row) * K + k0 + q * 4];
            *(float4*)&Bs[row][q * 4] =
                *(const float4*)&W1[(size_t)(n0 + row) * K + k0 + q * 4];
        }
        __syncthreads();
        #pragma unroll
        for (int g = 0; g < 8; ++g) {
            float4 af[8], bf[8];
            #pragma unroll
            for (int i = 0; i < 8; ++i)
                af[i] = *(const float4*)&As[ty + 16 * i][g * 4];
            #pragma unroll
            for (int j = 0; j < 8; ++j)
                bf[j] = *(const float4*)&Bs[tx + 16 * j][g * 4];
            #pragma unroll
            for (int kk = 0; kk < 4; ++kk) {
                #pragma unroll
                for (int i = 0; i < 8; ++i) {
                    const float a = ((const float*)&af[i])[kk];
                    #pragma unroll
                    for (int j = 0; j < 8; ++j)
                        p[i][j] = __builtin_fmaf(a, ((const float*)&bf[j])[kk], p[i][j]);
                }
            }
        }
        __syncthreads();
        const int ke = k0 + 32;
        if (ke == f0 || ke == K) {
            #pragma unroll
            for (int i = 0; i < 8; ++i)
                #pragma unroll
                for (int j = 0; j < 8; ++j) {
                    c[i][j] = vaddf(c[i][j], p[i][j]);
                    p[i][j] = 0.0f;
                }
        }
    }

    const float tau_m = decode_scalar(tau_mem_p, 10.0f);
    const float tau_s = decode_scalar(tau_syn_p, 5.0f);
    const float vth   = decode_scalar(v_thresh_p, 1.0f);
    const float vrs   = decode_scalar(v_reset_p, 0.0f);
    const int   ts    = decode_ts(ts_p);
    const float rs    = 1.0f / tau_s;
    const float rm    = 1.0f / tau_m;
    const float ivts  = 1.0f / (float)ts;

    #pragma unroll
    for (int j = 0; j < 8; ++j) {
        const int col    = n0 + tx + 16 * j;
        const float bias = b1[col];
        float cur[8], iv[8], vv[8], cnt[8];
        #pragma unroll
        for (int i = 0; i < 8; ++i) {
            cur[i] = vmulf(vaddf(c[i][j], bias), ivts);
            iv[i] = 0.0f; vv[i] = 0.0f; cnt[i] = 0.0f;
        }
        for (int tt = 0; tt < ts; ++tt) {
            #pragma unroll
            for (int i = 0; i < 8; ++i) {
                iv[i] = vaddf(vsubf(iv[i], vmulf(rs, iv[i])), cur[i]);
                vv[i] = vaddf(vsubf(vv[i], vmulf(rm, vv[i])), iv[i]);
                const bool s = (vv[i] >= vth);
                cnt[i] += s ? 1.0f : 0.0f;
                vv[i]   = s ? vrs : vv[i];
            }
        }
        #pragma unroll
        for (int i = 0; i < 8; ++i)
            spikes[(size_t)(m0 + ty + 16 * i) * N + col] = cnt[i];
    }
}

// -------- k2a: split-K partial GEMM (MFMA bf16-split), no bias --------------
__global__ __launch_bounds__(256) void k2_partial(
    const float* __restrict__ S, const float* __restrict__ W2,
    float* __restrict__ Pt,      // [4][M,N2] partials
    int M, int N2, int K2, int KC2)
{
    __shared__ __align__(16) short Sa[64 * 32];
    __shared__ __align__(16) short Bh[64 * 32];
    __shared__ __align__(16) short Bm[64 * 32];

    const int t    = threadIdx.x;
    const int l    = t & 63;
    const int w    = t >> 6;
    const int quad = l >> 4;
    const int r    = l & 15;
    const int wm   = w & 1;
    const int wn   = w >> 1;

    const int m0 = blockIdx.x * 64;
    const int n0 = blockIdx.y * 64;
    const int kz = blockIdx.z * KC2;
    float* __restrict__ outp = Pt + (size_t)blockIdx.z * M * N2;

    f32x4 acc[2][2] = {};

    for (int k0 = kz; k0 < kz + KC2; k0 += 32) {
        #pragma unroll
        for (int cc = 0; cc < 2; ++cc) {
            const int li  = cc * 256 + t;
            const int row = li >> 3;
            const int q   = li & 7;
            const float4 vs = *(const float4*)&S[(size_t)(m0 + row) * K2 + k0 + q * 4];
            *(short4*)&Sa[row * 32 + q * 4] =
                make_short4(bf16h(vs.x), bf16h(vs.y), bf16h(vs.z), bf16h(vs.w));
            const float4 vb = *(const float4*)&W2[(size_t)(n0 + row) * K2 + k0 + q * 4];
            short h[4], m_[4];
            split2(vb.x, h[0], m_[0]); split2(vb.y, h[1], m_[1]);
            split2(vb.z, h[2], m_[2]); split2(vb.w, h[3], m_[3]);
            *(short4*)&Bh[row * 32 + q * 4] = make_short4(h[0], h[1], h[2], h[3]);
            *(short4*)&Bm[row * 32 + q * 4] = make_short4(m_[0], m_[1], m_[2], m_[3]);
        }
        __syncthreads();

        bf16x8 af[2], bh[2], bm[2];
        #pragma unroll
        for (int i = 0; i < 2; ++i) {
            af[i] = *(const bf16x8*)&Sa[(wm * 32 + i * 16 + r) * 32 + quad * 8];
            bh[i] = *(const bf16x8*)&Bh[(wn * 32 + i * 16 + r) * 32 + quad * 8];
            bm[i] = *(const bf16x8*)&Bm[(wn * 32 + i * 16 + r) * 32 + quad * 8];
        }
        #pragma unroll
        for (int i = 0; i < 2; ++i)
            #pragma unroll
            for (int j = 0; j < 2; ++j) {
                acc[i][j] = __builtin_amdgcn_mfma_f32_16x16x32_bf16(af[i], bh[j], acc[i][j], 0, 0, 0);
                acc[i][j] = __builtin_amdgcn_mfma_f32_16x16x32_bf16(af[i], bm[j], acc[i][j], 0, 0, 0);
            }
        __syncthreads();
    }

    #pragma unroll
    for (int j = 0; j < 2; ++j) {
        const int col = n0 + wn * 32 + j * 16 + r;
        #pragma unroll
        for (int i = 0; i < 2; ++i) {
            const int rowb = m0 + wm * 32 + i * 16 + quad * 4;
            #pragma unroll
            for (int e = 0; e < 4; ++e)
                outp[(size_t)(rowb + e) * N2 + col] = acc[i][j][e];
        }
    }
}

// -------- k2b: out = p0+p1+p2+p3 + b2 ---------------------------------------
__global__ __launch_bounds__(256) void k2_combine(
    const float* __restrict__ Pt, const float* __restrict__ b2,
    float* __restrict__ out, int N2, int total4, size_t stride4)
{
    const int idx4 = blockIdx.x * 256 + threadIdx.x;
    if (idx4 >= total4) return;
    float4 s = ((const float4*)Pt)[idx4];
    #pragma unroll
    for (int z = 1; z < 4; ++z) {
        const float4 v = ((const float4*)Pt)[stride4 * z + idx4];
        s.x += v.x; s.y += v.y; s.z += v.z; s.w += v.w;
    }
    const float4 bb = *(const float4*)&b2[(idx4 * 4) % N2];
    s.x += bb.x; s.y += bb.y; s.z += bb.z; s.w += bb.w;
    ((float4*)out)[idx4] = s;
}

// -------- fallback k2 (verified R4-R20): full-K, bias fused -----------------
__global__ __launch_bounds__(256) void k2_gemm(
    const float* __restrict__ S, const float* __restrict__ W2,
    const float* __restrict__ b2, float* __restrict__ out,
    int M, int N2, int K2)
{
    __shared__ __align__(16) short Sa[64 * 32];
    __shared__ __align__(16) short Bh[64 * 32];
    __shared__ __align__(16) short Bm[64 * 32];

    const int t    = threadIdx.x;
    const int l    = t & 63;
    const int w    = t >> 6;
    const int quad = l >> 4;
    const int r    = l & 15;
    const int wm   = w & 1;
    const int wn   = w >> 1;

    const int m0 = blockIdx.x * 64;
    const int n0 = blockIdx.y * 64;

    f32x4 acc[2][2] = {};

    for (int k0 = 0; k0 < K2; k0 += 32) {
        #pragma unroll
        for (int cc = 0; cc < 2; ++cc) {
            const int li  = cc * 256 + t;
            const int row = li >> 3;
            const int q   = li & 7;
            const float4 vs = *(const float4*)&S[(size_t)(m0 + row) * K2 + k0 + q * 4];
            *(short4*)&Sa[row * 32 + q * 4] =
                make_short4(bf16h(vs.x), bf16h(vs.y), bf16h(vs.z), bf16h(vs.w));
            const float4 vb = *(const float4*)&W2[(size_t)(n0 + row) * K2 + k0 + q * 4];
            short h[4], m_[4];
            split2(vb.x, h[0], m_[0]); split2(vb.y, h[1], m_[1]);
            split2(vb.z, h[2], m_[2]); split2(vb.w, h[3], m_[3]);
            *(short4*)&Bh[row * 32 + q * 4] = make_short4(h[0], h[1], h[2], h[3]);
            *(short4*)&Bm[row * 32 + q * 4] = make_short4(m_[0], m_[1], m_[2], m_[3]);
        }
        __syncthreads();

        bf16x8 af[2], bh[2], bm[2];
        #pragma unroll
        for (int i = 0; i < 2; ++i) {
            af[i] = *(const bf16x8*)&Sa[(wm * 32 + i * 16 + r) * 32 + quad * 8];
            bh[i] = *(const bf16x8*)&Bh[(wn * 32 + i * 16 + r) * 32 + quad * 8];
            bm[i] = *(const bf16x8*)&Bm[(wn * 32 + i * 16 + r) * 32 + quad * 8];
        }
        #pragma unroll
        for (int i = 0; i < 2; ++i)
            #pragma unroll
            for (int j = 0; j < 2; ++j) {
                acc[i][j] = __builtin_amdgcn_mfma_f32_16x16x32_bf16(af[i], bh[j], acc[i][j], 0, 0, 0);
                acc[i][j] = __builtin_amdgcn_mfma_f32_16x16x32_bf16(af[i], bm[j], acc[i][j], 0, 0, 0);
            }
        __syncthreads();
    }

    #pragma unroll
    for (int j = 0; j < 2; ++j) {
        const int col = n0 + wn * 32 + j * 16 + r;
        const float bias = b2[col];
        #pragma unroll
        for (int i = 0; i < 2; ++i) {
            const int rowb = m0 + wm * 32 + i * 16 + quad * 4;
            #pragma unroll
            for (int e = 0; e < 4; ++e)
                out[(size_t)(rowb + e) * N2 + col] = __fadd_rn(acc[i][j][e], bias);
        }
    }
}

extern "C" void kernel_launch(void* const* d_in, const int* in_sizes, int n_in,
                              void* d_out, int out_size, void* d_ws, size_t ws_size,
                              hipStream_t stream) {
    (void)n_in; (void)out_size;

    const float* X  = (const float*)d_in[0];
    const float* W1 = (const float*)d_in[1];
    const float* b1 = (const float*)d_in[2];
    const float* W2 = (const float*)d_in[3];
    const float* b2 = (const float*)d_in[4];
    const void* tau_mem = d_in[5];
    const void* tau_syn = d_in[6];
    const void* vth     = d_in[7];
    const void* vrs     = d_in[8];
    const void* ts      = d_in[11];

    const int H   = in_sizes[2];             // 2048
    const int IN  = in_sizes[1] / H;         // 1024
    const int OUT = in_sizes[4];             // 256
    const int B   = in_sizes[0] / IN;        // 4096

    float* out    = (float*)d_out;           // [B, OUT] fp32
    float* spikes = out + (size_t)B * OUT;   // [B, H]  fp32

    const int KC = 512;                      // VERIFIED: AOCL-BLIS zen KC
    const size_t panel_bytes = (size_t)B * H * sizeof(float);
    const bool ws_ok = (IN == 2 * KC) && (ws_size >= panel_bytes) &&
                       ((uintptr_t)d_ws % 16 == 0);

    if (ws_ok) {
        float* P1 = (float*)d_ws;
        dim3 g1(B / 128, H / 128, 2);
        k1_panel_gemm<<<g1, 256, 0, stream>>>(X, W1, spikes, P1, B, H, IN, KC);

        const int total4 = (B * H) / 4;
        k1_combine_scan<<<(total4 + 255) / 256, 256, 0, stream>>>(
            spikes, P1, b1, tau_mem, tau_syn, vth, vrs, ts, spikes, H, total4);
    } else {
        dim3 g1(B / 128, H / 128);
        k1_f32chain_snn<<<g1, 256, 0, stream>>>(X, W1, b1, tau_mem, tau_syn, vth, vrs, ts,
                                                spikes, B, H, IN, KC);
    }

    const int KC2 = 512;
    const size_t k2_part_bytes = 4 * (size_t)B * OUT * sizeof(float);
    if (ws_ok && H == 4 * KC2 && ws_size >= k2_part_bytes) {
        float* Pt = (float*)d_ws;
        dim3 g2(B / 64, OUT / 64, 4);
        k2_partial<<<g2, 256, 0, stream>>>(spikes, W2, Pt, B, OUT, H, KC2);
        const int total4 = (B * OUT) / 4;
        k2_combine<<<(total4 + 255) / 256, 256, 0, stream>>>(
            Pt, b2, out, OUT, total4, (size_t)B * OUT / 4);
    } else {
        dim3 g2(B / 64, OUT / 64);
        k2_gemm<<<g2, 256, 0, stream>>>(spikes, W2, b2, out, B, OUT, H);
    }
}

// Round 22
// 468.175 us; speedup vs baseline: 1.2174x; 1.2174x over previous
//
#include <hip/hip_runtime.h>
#include <hip/hip_bf16.h>
#include <stdint.h>

typedef __attribute__((ext_vector_type(8))) short bf16x8;
typedef __attribute__((ext_vector_type(4))) float f32x4;

// Contraction-proof single f32 ops (np emulation must stay unfused).
__device__ __forceinline__ float vmulf(float a, float b) {
    float d; asm volatile("v_mul_f32 %0, %1, %2" : "=v"(d) : "v"(a), "v"(b)); return d;
}
__device__ __forceinline__ float vaddf(float a, float b) {
    float d; asm volatile("v_add_f32 %0, %1, %2" : "=v"(d) : "v"(a), "v"(b)); return d;
}
__device__ __forceinline__ float vsubf(float a, float b) {
    float d; asm volatile("v_sub_f32 %0, %1, %2" : "=v"(d) : "v"(a), "v"(b)); return d;
}

__device__ __forceinline__ short bf16h(float v) {
    __hip_bfloat16 h = __float2bfloat16(v);
    return *(short*)&h;
}
__device__ __forceinline__ float bf16f(short s) {
    return __uint_as_float(((unsigned int)(unsigned short)s) << 16);
}
__device__ __forceinline__ void split2(float v, short& h, short& m) {
    h = bf16h(v);
    m = bf16h(__fsub_rn(v, bf16f(h)));
}

__device__ __forceinline__ float decode_scalar(const void* p, float dflt) {
    float f = *(const float*)p;
    if (!(f == f) || fabsf(f) > 1.0e6f) return dflt;
    return f;
}
__device__ __forceinline__ int decode_ts(const void* p) {
    int w = *(const int*)p;
    if (w >= 1 && w <= 100000) return w;
    return 32;
}

#define LDA 36   // LDS row stride: 16B-aligned b128; A bcast, B 2-way (free)

// -------- k1a: one BLIS KC=512 panel per block (exact ascending-k chain) ----
// Reference (VERIFIED R17-R21) = AOCL-BLIS zen sgemm: exact KC=512 panels,
// sequential ascending-k IEEE-FMA chain per C element, C = P0 + P1 in order.
// R22: R20's LDS A+B structure (R21's A-from-global regressed: vmem latency
// bound) + REGISTER PREFETCH pipeline: tile t+1's global loads issue during
// tile t's compute (vmcnt independent of the LDS-read lgkmcnt path).
__global__ __launch_bounds__(256) void k1_panel_gemm(
    const float* __restrict__ X,    // [M,K] fp32
    const float* __restrict__ W1,   // [N,K] fp32
    float* __restrict__ P0,         // [M,N] panel-0 out (spikes buffer)
    float* __restrict__ P1,         // [M,N] panel-1 out (workspace)
    int M, int N, int K, int KC)
{
    __shared__ float As[128][LDA];
    __shared__ float Bs[128][LDA];

    const int t  = threadIdx.x;
    const int tx = t & 15;
    const int ty = t >> 4;
    const int m0 = blockIdx.x * 128;
    const int n0 = blockIdx.y * 128;
    const int kz = blockIdx.z * KC;
    float* __restrict__ Pout = blockIdx.z ? P1 : P0;

    // Staging assignment: thread covers 4 (row,q) slots for A and B each.
    int srow[4], sq[4];
    const float* gA[4];
    const float* gB[4];
    #pragma unroll
    for (int cc = 0; cc < 4; ++cc) {
        const int li = cc * 256 + t;
        srow[cc] = li >> 3;
        sq[cc]   = li & 7;
        gA[cc] = X  + (size_t)(m0 + srow[cc]) * K + kz + sq[cc] * 4;
        gB[cc] = W1 + (size_t)(n0 + srow[cc]) * K + kz + sq[cc] * 4;
    }

    float p[8][8] = {};   // this panel's sequential chain
    float4 ra[4], rb[4];  // prefetch registers

    // Preload tile 0.
    #pragma unroll
    for (int cc = 0; cc < 4; ++cc) {
        ra[cc] = *(const float4*)gA[cc];
        rb[cc] = *(const float4*)gB[cc];
    }

    for (int kt = 0; kt < KC; kt += 32) {
        // Commit prefetched tile to LDS.
        #pragma unroll
        for (int cc = 0; cc < 4; ++cc) {
            *(float4*)&As[srow[cc]][sq[cc] * 4] = ra[cc];
            *(float4*)&Bs[srow[cc]][sq[cc] * 4] = rb[cc];
        }
        __syncthreads();

        // Issue next tile's loads now; they fly during compute below.
        if (kt + 32 < KC) {
            #pragma unroll
            for (int cc = 0; cc < 4; ++cc) {
                ra[cc] = *(const float4*)(gA[cc] + kt + 32);
                rb[cc] = *(const float4*)(gB[cc] + kt + 32);
            }
        }

        #pragma unroll
        for (int g = 0; g < 8; ++g) {
            float4 af[8], bf[8];
            #pragma unroll
            for (int i = 0; i < 8; ++i)
                af[i] = *(const float4*)&As[ty + 16 * i][g * 4];
            #pragma unroll
            for (int j = 0; j < 8; ++j)
                bf[j] = *(const float4*)&Bs[tx + 16 * j][g * 4];
            #pragma unroll
            for (int kk = 0; kk < 4; ++kk) {
                #pragma unroll
                for (int i = 0; i < 8; ++i) {
                    const float a = ((const float*)&af[i])[kk];
                    #pragma unroll
                    for (int j = 0; j < 8; ++j)
                        p[i][j] = __builtin_fmaf(a, ((const float*)&bf[j])[kk], p[i][j]);
                }
            }
        }
        __syncthreads();
    }

    #pragma unroll
    for (int i = 0; i < 8; ++i) {
        const size_t rowb = (size_t)(m0 + ty + 16 * i) * N;
        #pragma unroll
        for (int j = 0; j < 8; ++j)
            Pout[rowb + n0 + tx + 16 * j] = p[i][j];
    }
}

// -------- k1b: fold c = P0 + P1 (BLIS order) + exact f32 asm-unfused scan ---
__global__ __launch_bounds__(256) void k1_combine_scan(
    const float* __restrict__ P0,
    const float* __restrict__ P1,
    const float* __restrict__ b1,
    const void* tau_mem_p, const void* tau_syn_p,
    const void* v_thresh_p, const void* v_reset_p, const void* ts_p,
    float* __restrict__ spikes, int N, int total4)
{
    const int idx4 = blockIdx.x * 256 + threadIdx.x;
    if (idx4 >= total4) return;

    const float tau_m = decode_scalar(tau_mem_p, 10.0f);
    const float tau_s = decode_scalar(tau_syn_p, 5.0f);
    const float vth   = decode_scalar(v_thresh_p, 1.0f);
    const float vrs   = decode_scalar(v_reset_p, 0.0f);
    const int   ts    = decode_ts(ts_p);
    const float rs    = 1.0f / tau_s;
    const float rm    = 1.0f / tau_m;
    const float ivts  = 1.0f / (float)ts;

    const float4 a = ((const float4*)P0)[idx4];
    const float4 b = ((const float4*)P1)[idx4];
    const int col0 = (idx4 * 4) % N;
    const float4 bb = *(const float4*)&b1[col0];

    float cur[4], iv[4], vv[4], cnt[4];
    const float av[4] = {a.x, a.y, a.z, a.w};
    const float bv[4] = {b.x, b.y, b.z, b.w};
    const float bbv[4] = {bb.x, bb.y, bb.z, bb.w};
    #pragma unroll
    for (int e = 0; e < 4; ++e) {
        const float c = vaddf(av[e], bv[e]);         // BLIS fold: P0 + P1
        cur[e] = vmulf(vaddf(c, bbv[e]), ivts);      // exact /32
        iv[e] = 0.0f; vv[e] = 0.0f; cnt[e] = 0.0f;
    }
    for (int tt = 0; tt < ts; ++tt) {
        #pragma unroll
        for (int e = 0; e < 4; ++e) {
            iv[e] = vaddf(vsubf(iv[e], vmulf(rs, iv[e])), cur[e]);
            vv[e] = vaddf(vsubf(vv[e], vmulf(rm, vv[e])), iv[e]);
            const bool s = (vv[e] >= vth);
            cnt[e] += s ? 1.0f : 0.0f;
            vv[e]   = s ? vrs : vv[e];
        }
    }
    ((float4*)spikes)[idx4] = make_float4(cnt[0], cnt[1], cnt[2], cnt[3]);
}

// -------- fallback k1 (R18, verified): used when ws_size is too small -------
__global__ __launch_bounds__(256) void k1_f32chain_snn(
    const float* __restrict__ X, const float* __restrict__ W1,
    const float* __restrict__ b1,
    const void* tau_mem_p, const void* tau_syn_p,
    const void* v_thresh_p, const void* v_reset_p, const void* ts_p,
    float* __restrict__ spikes, int M, int N, int K, int f0)
{
    __shared__ float As[128][LDA];
    __shared__ float Bs[128][LDA];

    const int t  = threadIdx.x;
    const int tx = t & 15;
    const int ty = t >> 4;
    const int m0 = blockIdx.x * 128;
    const int n0 = blockIdx.y * 128;

    float c[8][8] = {};
    float p[8][8] = {};

    for (int k0 = 0; k0 < K; k0 += 32) {
        #pragma unroll
        for (int cc = 0; cc < 4; ++cc) {
            const int li  = cc * 256 + t;
            const int row = li >> 3;
            const int q   = li & 7;
            *(float4*)&As[row][q * 4] =
                *(const float4*)&X[(size_t)(m0 + row) * K + k0 + q * 4];
            *(float4*)&Bs[row][q * 4] =
                *(const float4*)&W1[(size_t)(n0 + row) * K + k0 + q * 4];
        }
        __syncthreads();
        #pragma unroll
        for (int g = 0; g < 8; ++g) {
            float4 af[8], bf[8];
            #pragma unroll
            for (int i = 0; i < 8; ++i)
                af[i] = *(const float4*)&As[ty + 16 * i][g * 4];
            #pragma unroll
            for (int j = 0; j < 8; ++j)
                bf[j] = *(const float4*)&Bs[tx + 16 * j][g * 4];
            #pragma unroll
            for (int kk = 0; kk < 4; ++kk) {
                #pragma unroll
                for (int i = 0; i < 8; ++i) {
                    const float a = ((const float*)&af[i])[kk];
                    #pragma unroll
                    for (int j = 0; j < 8; ++j)
                        p[i][j] = __builtin_fmaf(a, ((const float*)&bf[j])[kk], p[i][j]);
                }
            }
        }
        __syncthreads();
        const int ke = k0 + 32;
        if (ke == f0 || ke == K) {
            #pragma unroll
            for (int i = 0; i < 8; ++i)
                #pragma unroll
                for (int j = 0; j < 8; ++j) {
                    c[i][j] = vaddf(c[i][j], p[i][j]);
                    p[i][j] = 0.0f;
                }
        }
    }

    const float tau_m = decode_scalar(tau_mem_p, 10.0f);
    const float tau_s = decode_scalar(tau_syn_p, 5.0f);
    const float vth   = decode_scalar(v_thresh_p, 1.0f);
    const float vrs   = decode_scalar(v_reset_p, 0.0f);
    const int   ts    = decode_ts(ts_p);
    const float rs    = 1.0f / tau_s;
    const float rm    = 1.0f / tau_m;
    const float ivts  = 1.0f / (float)ts;

    #pragma unroll
    for (int j = 0; j < 8; ++j) {
        const int col    = n0 + tx + 16 * j;
        const float bias = b1[col];
        float cur[8], iv[8], vv[8], cnt[8];
        #pragma unroll
        for (int i = 0; i < 8; ++i) {
            cur[i] = vmulf(vaddf(c[i][j], bias), ivts);
            iv[i] = 0.0f; vv[i] = 0.0f; cnt[i] = 0.0f;
        }
        for (int tt = 0; tt < ts; ++tt) {
            #pragma unroll
            for (int i = 0; i < 8; ++i) {
                iv[i] = vaddf(vsubf(iv[i], vmulf(rs, iv[i])), cur[i]);
                vv[i] = vaddf(vsubf(vv[i], vmulf(rm, vv[i])), iv[i]);
                const bool s = (vv[i] >= vth);
                cnt[i] += s ? 1.0f : 0.0f;
                vv[i]   = s ? vrs : vv[i];
            }
        }
        #pragma unroll
        for (int i = 0; i < 8; ++i)
            spikes[(size_t)(m0 + ty + 16 * i) * N + col] = cnt[i];
    }
}

// -------- k2a: split-K partial GEMM (MFMA bf16-split), no bias --------------
__global__ __launch_bounds__(256) void k2_partial(
    const float* __restrict__ S, const float* __restrict__ W2,
    float* __restrict__ Pt,      // [4][M,N2] partials
    int M, int N2, int K2, int KC2)
{
    __shared__ __align__(16) short Sa[64 * 32];
    __shared__ __align__(16) short Bh[64 * 32];
    __shared__ __align__(16) short Bm[64 * 32];

    const int t    = threadIdx.x;
    const int l    = t & 63;
    const int w    = t >> 6;
    const int quad = l >> 4;
    const int r    = l & 15;
    const int wm   = w & 1;
    const int wn   = w >> 1;

    const int m0 = blockIdx.x * 64;
    const int n0 = blockIdx.y * 64;
    const int kz = blockIdx.z * KC2;
    float* __restrict__ outp = Pt + (size_t)blockIdx.z * M * N2;

    f32x4 acc[2][2] = {};

    for (int k0 = kz; k0 < kz + KC2; k0 += 32) {
        #pragma unroll
        for (int cc = 0; cc < 2; ++cc) {
            const int li  = cc * 256 + t;
            const int row = li >> 3;
            const int q   = li & 7;
            const float4 vs = *(const float4*)&S[(size_t)(m0 + row) * K2 + k0 + q * 4];
            *(short4*)&Sa[row * 32 + q * 4] =
                make_short4(bf16h(vs.x), bf16h(vs.y), bf16h(vs.z), bf16h(vs.w));
            const float4 vb = *(const float4*)&W2[(size_t)(n0 + row) * K2 + k0 + q * 4];
            short h[4], m_[4];
            split2(vb.x, h[0], m_[0]); split2(vb.y, h[1], m_[1]);
            split2(vb.z, h[2], m_[2]); split2(vb.w, h[3], m_[3]);
            *(short4*)&Bh[row * 32 + q * 4] = make_short4(h[0], h[1], h[2], h[3]);
            *(short4*)&Bm[row * 32 + q * 4] = make_short4(m_[0], m_[1], m_[2], m_[3]);
        }
        __syncthreads();

        bf16x8 af[2], bh[2], bm[2];
        #pragma unroll
        for (int i = 0; i < 2; ++i) {
            af[i] = *(const bf16x8*)&Sa[(wm * 32 + i * 16 + r) * 32 + quad * 8];
            bh[i] = *(const bf16x8*)&Bh[(wn * 32 + i * 16 + r) * 32 + quad * 8];
            bm[i] = *(const bf16x8*)&Bm[(wn * 32 + i * 16 + r) * 32 + quad * 8];
        }
        #pragma unroll
        for (int i = 0; i < 2; ++i)
            #pragma unroll
            for (int j = 0; j < 2; ++j) {
                acc[i][j] = __builtin_amdgcn_mfma_f32_16x16x32_bf16(af[i], bh[j], acc[i][j], 0, 0, 0);
                acc[i][j] = __builtin_amdgcn_mfma_f32_16x16x32_bf16(af[i], bm[j], acc[i][j], 0, 0, 0);
            }
        __syncthreads();
    }

    #pragma unroll
    for (int j = 0; j < 2; ++j) {
        const int col = n0 + wn * 32 + j * 16 + r;
        #pragma unroll
        for (int i = 0; i < 2; ++i) {
            const int rowb = m0 + wm * 32 + i * 16 + quad * 4;
            #pragma unroll
            for (int e = 0; e < 4; ++e)
                outp[(size_t)(rowb + e) * N2 + col] = acc[i][j][e];
        }
    }
}

// -------- k2b: out = p0+p1+p2+p3 + b2 ---------------------------------------
__global__ __launch_bounds__(256) void k2_combine(
    const float* __restrict__ Pt, const float* __restrict__ b2,
    float* __restrict__ out, int N2, int total4, size_t stride4)
{
    const int idx4 = blockIdx.x * 256 + threadIdx.x;
    if (idx4 >= total4) return;
    float4 s = ((const float4*)Pt)[idx4];
    #pragma unroll
    for (int z = 1; z < 4; ++z) {
        const float4 v = ((const float4*)Pt)[stride4 * z + idx4];
        s.x += v.x; s.y += v.y; s.z += v.z; s.w += v.w;
    }
    const float4 bb = *(const float4*)&b2[(idx4 * 4) % N2];
    s.x += bb.x; s.y += bb.y; s.z += bb.z; s.w += bb.w;
    ((float4*)out)[idx4] = s;
}

// -------- fallback k2 (verified R4-R21): full-K, bias fused -----------------
__global__ __launch_bounds__(256) void k2_gemm(
    const float* __restrict__ S, const float* __restrict__ W2,
    const float* __restrict__ b2, float* __restrict__ out,
    int M, int N2, int K2)
{
    __shared__ __align__(16) short Sa[64 * 32];
    __shared__ __align__(16) short Bh[64 * 32];
    __shared__ __align__(16) short Bm[64 * 32];

    const int t    = threadIdx.x;
    const int l    = t & 63;
    const int w    = t >> 6;
    const int quad = l >> 4;
    const int r    = l & 15;
    const int wm   = w & 1;
    const int wn   = w >> 1;

    const int m0 = blockIdx.x * 64;
    const int n0 = blockIdx.y * 64;

    f32x4 acc[2][2] = {};

    for (int k0 = 0; k0 < K2; k0 += 32) {
        #pragma unroll
        for (int cc = 0; cc < 2; ++cc) {
            const int li  = cc * 256 + t;
            const int row = li >> 3;
            const int q   = li & 7;
            const float4 vs = *(const float4*)&S[(size_t)(m0 + row) * K2 + k0 + q * 4];
            *(short4*)&Sa[row * 32 + q * 4] =
                make_short4(bf16h(vs.x), bf16h(vs.y), bf16h(vs.z), bf16h(vs.w));
            const float4 vb = *(const float4*)&W2[(size_t)(n0 + row) * K2 + k0 + q * 4];
            short h[4], m_[4];
            split2(vb.x, h[0], m_[0]); split2(vb.y, h[1], m_[1]);
            split2(vb.z, h[2], m_[2]); split2(vb.w, h[3], m_[3]);
            *(short4*)&Bh[row * 32 + q * 4] = make_short4(h[0], h[1], h[2], h[3]);
            *(short4*)&Bm[row * 32 + q * 4] = make_short4(m_[0], m_[1], m_[2], m_[3]);
        }
        __syncthreads();

        bf16x8 af[2], bh[2], bm[2];
        #pragma unroll
        for (int i = 0; i < 2; ++i) {
            af[i] = *(const bf16x8*)&Sa[(wm * 32 + i * 16 + r) * 32 + quad * 8];
            bh[i] = *(const bf16x8*)&Bh[(wn * 32 + i * 16 + r) * 32 + quad * 8];
            bm[i] = *(const bf16x8*)&Bm[(wn * 32 + i * 16 + r) * 32 + quad * 8];
        }
        #pragma unroll
        for (int i = 0; i < 2; ++i)
            #pragma unroll
            for (int j = 0; j < 2; ++j) {
                acc[i][j] = __builtin_amdgcn_mfma_f32_16x16x32_bf16(af[i], bh[j], acc[i][j], 0, 0, 0);
                acc[i][j] = __builtin_amdgcn_mfma_f32_16x16x32_bf16(af[i], bm[j], acc[i][j], 0, 0, 0);
            }
        __syncthreads();
    }

    #pragma unroll
    for (int j = 0; j < 2; ++j) {
        const int col = n0 + wn * 32 + j * 16 + r;
        const float bias = b2[col];
        #pragma unroll
        for (int i = 0; i < 2; ++i) {
            const int rowb = m0 + wm * 32 + i * 16 + quad * 4;
            #pragma unroll
            for (int e = 0; e < 4; ++e)
                out[(size_t)(rowb + e) * N2 + col] = __fadd_rn(acc[i][j][e], bias);
        }
    }
}

extern "C" void kernel_launch(void* const* d_in, const int* in_sizes, int n_in,
                              void* d_out, int out_size, void* d_ws, size_t ws_size,
                              hipStream_t stream) {
    (void)n_in; (void)out_size;

    const float* X  = (const float*)d_in[0];
    const float* W1 = (const float*)d_in[1];
    const float* b1 = (const float*)d_in[2];
    const float* W2 = (const float*)d_in[3];
    const float* b2 = (const float*)d_in[4];
    const void* tau_mem = d_in[5];
    const void* tau_syn = d_in[6];
    const void* vth     = d_in[7];
    const void* vrs     = d_in[8];
    const void* ts      = d_in[11];

    const int H   = in_sizes[2];             // 2048
    const int IN  = in_sizes[1] / H;         // 1024
    const int OUT = in_sizes[4];             // 256
    const int B   = in_sizes[0] / IN;        // 4096

    float* out    = (float*)d_out;           // [B, OUT] fp32
    float* spikes = out + (size_t)B * OUT;   // [B, H]  fp32

    const int KC = 512;                      // VERIFIED: AOCL-BLIS zen KC
    const size_t panel_bytes = (size_t)B * H * sizeof(float);
    const bool ws_ok = (IN == 2 * KC) && (ws_size >= panel_bytes) &&
                       ((uintptr_t)d_ws % 16 == 0);

    if (ws_ok) {
        float* P1 = (float*)d_ws;
        dim3 g1(B / 128, H / 128, 2);
        k1_panel_gemm<<<g1, 256, 0, stream>>>(X, W1, spikes, P1, B, H, IN, KC);

        const int total4 = (B * H) / 4;
        k1_combine_scan<<<(total4 + 255) / 256, 256, 0, stream>>>(
            spikes, P1, b1, tau_mem, tau_syn, vth, vrs, ts, spikes, H, total4);
    } else {
        dim3 g1(B / 128, H / 128);
        k1_f32chain_snn<<<g1, 256, 0, stream>>>(X, W1, b1, tau_mem, tau_syn, vth, vrs, ts,
                                                spikes, B, H, IN, KC);
    }

    const int KC2 = 512;
    const size_t k2_part_bytes = 4 * (size_t)B * OUT * sizeof(float);
    if (ws_ok && H == 4 * KC2 && ws_size >= k2_part_bytes) {
        float* Pt = (float*)d_ws;
        dim3 g2(B / 64, OUT / 64, 4);
        k2_partial<<<g2, 256, 0, stream>>>(spikes, W2, Pt, B, OUT, H, KC2);
        const int total4 = (B * OUT) / 4;
        k2_combine<<<(total4 + 255) / 256, 256, 0, stream>>>(
            Pt, b2, out, OUT, total4, (size_t)B * OUT / 4);
    } else {
        dim3 g2(B / 64, OUT / 64);
        k2_gemm<<<g2, 256, 0, stream>>>(spikes, W2, b2, out, B, OUT, H);
    }
}